// Round 14
// baseline (265.297 us; speedup 1.0000x reference)
//
#include <hip/hip_runtime.h>
#include <hip/hip_bf16.h>

#define N_NODES 50000
#define N_EDGES 800000
#define DIM 96
#define CHB 12  // bf16 row = 96*2B = 12 x 16B chunks

#define EPB 2048                                   // edges per partition block
#define NB_E ((N_EDGES + EPB - 1) / EPB)           // 391
#define NBKT ((N_NODES + 255) / 256)               // 196 buckets of 256 nodes
#define NTILES ((N_NODES + 63) / 64)               // 782 layer tiles
#define PREP_ITEMS (3 * DIM * DIM + 3 * DIM)       // 27936
#define LROW 112                                   // LDS row stride in bf16 (224B, 16B-aligned)

typedef __attribute__((ext_vector_type(8))) short short8;  // 8 bf16 = 4 VGPRs
typedef __attribute__((ext_vector_type(4))) float f32x4;

// R12 lesson: cooperative grid.sync() costs ~250us/sync on MI355X (8 non-coherent
// XCD L2s). Kernel boundaries are the cheap grid barrier. R6 lesson: fusion is only
// safe when the fused kernel keeps gather-grade occupancy (small LDS, no W staging).

// ---------------- helpers ----------------

__device__ __forceinline__ unsigned short f2bf(float f) {  // RNE fp32->bf16 (finite)
    unsigned u = __float_as_uint(f);
    u += 0x7FFFu + ((u >> 16) & 1u);
    return (unsigned short)(u >> 16);
}

__device__ __forceinline__ int good_halves(unsigned w) {
    unsigned lo = w & 0xFFFFu, hi = w >> 16;
    unsigned e0 = (lo >> 7) & 0xFF, e1 = (hi >> 7) & 0xFF;
    int g = 0;
    if (lo == 0 || (e0 >= 100 && e0 <= 140)) ++g;
    if (hi == 0 || (e1 >= 100 && e1 <= 140)) ++g;
    return g;
}

__device__ __forceinline__ float rdval(const void* p, int i, int isbf) {
    return isbf ? __bfloat162float(((const __hip_bfloat16*)p)[i]) : ((const float*)p)[i];
}

__device__ __forceinline__ int load_idx(const int* __restrict__ p, int e, int is64) {
    return p[is64 ? (e << 1) : e];
}

__device__ __forceinline__ void acc8(float* a, uint4 q) {
    a[0] += __uint_as_float(q.x << 16);
    a[1] += __uint_as_float(q.x & 0xFFFF0000u);
    a[2] += __uint_as_float(q.y << 16);
    a[3] += __uint_as_float(q.y & 0xFFFF0000u);
    a[4] += __uint_as_float(q.z << 16);
    a[5] += __uint_as_float(q.z & 0xFFFF0000u);
    a[6] += __uint_as_float(q.w << 16);
    a[7] += __uint_as_float(q.w & 0xFFFF0000u);
}

// ---------------- pass 1: per-block bucket counts + flag publication ----------------

__global__ __launch_bounds__(256) void part_count(const int* __restrict__ src,
                                                  const int* __restrict__ dst,
                                                  const unsigned* __restrict__ hw,
                                                  const unsigned* __restrict__ ww,
                                                  int* __restrict__ cntD,
                                                  int* __restrict__ cntS,
                                                  int* __restrict__ flags) {
    const unsigned* sw = (const unsigned*)src;
    int zeros = 0;
    for (int i = 0; i < 64; ++i) zeros += (sw[2 * i + 1] == 0u) ? 1 : 0;
    int is64 = (zeros >= 60) ? 1 : 0;

    __shared__ int lcD[256], lcS[256];
    int b = blockIdx.x, t = threadIdx.x;
    lcD[t] = 0; lcS[t] = 0;
    __syncthreads();
    int base = b * EPB;
#pragma unroll
    for (int i = 0; i < EPB / 256; ++i) {
        int e = base + i * 256 + t;
        if (e < N_EDGES) {
            int d = load_idx(dst, e, is64);
            int s = load_idx(src, e, is64);
            atomicAdd(&lcD[d >> 8], 1);
            atomicAdd(&lcS[s >> 8], 1);
        }
    }
    __syncthreads();
    cntD[b * 256 + t] = lcD[t];
    cntS[b * 256 + t] = lcS[t];

    if (b == 0) {
        if (t == 0) flags[2] = is64;
        if (t == 1) {
            int good = 0;
            for (int i = 0; i < 128; ++i) good += good_halves(hw[i]);
            flags[0] = (good >= 226) ? 1 : 0;
        }
        if (t == 2) {
            int good = 0;
            for (int i = 0; i < 128; ++i) good += good_halves(ww[i]);
            flags[1] = (good >= 226) ? 1 : 0;
        }
    }
}

// ---------------- pass 2: per-bucket scan over blocks + folded W^T/bias prep --------

__global__ __launch_bounds__(256) void scan_buckets(int* __restrict__ cntD,
                                                    int* __restrict__ cntS,
                                                    int* __restrict__ btotD,
                                                    int* __restrict__ btotS,
                                                    const void* __restrict__ W0,
                                                    const void* __restrict__ W1,
                                                    const void* __restrict__ W2,
                                                    const void* __restrict__ b0p,
                                                    const void* __restrict__ b1p,
                                                    const void* __restrict__ b2p,
                                                    unsigned short* __restrict__ WT,
                                                    float* __restrict__ biasc,
                                                    const int* __restrict__ flags) {
    __shared__ int sm[256];
    int k = blockIdx.x, t = threadIdx.x;
    int b0 = 2 * t, b1 = 2 * t + 1;
    int v0 = (b0 < NB_E) ? cntD[b0 * 256 + k] : 0;
    int v1 = (b1 < NB_E) ? cntD[b1 * 256 + k] : 0;
    int pair = v0 + v1;
    sm[t] = pair;
    __syncthreads();
    for (int off = 1; off < 256; off <<= 1) {
        int u = (t >= off) ? sm[t - off] : 0;
        __syncthreads();
        sm[t] += u;
        __syncthreads();
    }
    int excl = sm[t] - pair;
    if (b0 < NB_E) cntD[b0 * 256 + k] = excl;
    if (b1 < NB_E) cntD[b1 * 256 + k] = excl + v0;
    if (t == 255) btotD[k] = sm[255];
    __syncthreads();
    v0 = (b0 < NB_E) ? cntS[b0 * 256 + k] : 0;
    v1 = (b1 < NB_E) ? cntS[b1 * 256 + k] : 0;
    pair = v0 + v1;
    sm[t] = pair;
    __syncthreads();
    for (int off = 1; off < 256; off <<= 1) {
        int u = (t >= off) ? sm[t - off] : 0;
        __syncthreads();
        sm[t] += u;
        __syncthreads();
    }
    excl = sm[t] - pair;
    if (b0 < NB_E) cntS[b0 * 256 + k] = excl;
    if (b1 < NB_E) cntS[b1 * 256 + k] = excl + v0;
    if (t == 255) btotS[k] = sm[255];

    // folded weight prep: one item per (block,thread), 27936 < 65536
    int idx = k * 256 + t;
    if (idx < PREP_ITEMS) {
        int wbf = flags[1];
        if (idx < 3 * DIM * DIM) {
            int l = idx / (DIM * DIM);
            int i = idx - l * DIM * DIM;
            int kk = i / DIM, n = i - kk * DIM;
            const void* Wp = (l == 0) ? W0 : (l == 1) ? W1 : W2;
            WT[l * DIM * DIM + n * DIM + kk] = f2bf(rdval(Wp, i, wbf));
        } else {
            int j = idx - 3 * DIM * DIM;
            int l = j / DIM, c = j - l * DIM;
            const void* bp = (l == 0) ? b0p : (l == 1) ? b1p : b2p;
            biasc[j] = rdval(bp, c, wbf);
        }
    }
}

// ---------------- pass 3: scatter into buckets (bases re-scanned in LDS) ----------

__global__ __launch_bounds__(256) void part_scatter(const int* __restrict__ src,
                                                    const int* __restrict__ dst,
                                                    const int* __restrict__ offD,
                                                    const int* __restrict__ offS,
                                                    const int* __restrict__ btotD,
                                                    const int* __restrict__ btotS,
                                                    unsigned* __restrict__ epack,
                                                    unsigned char* __restrict__ sloc,
                                                    const int* __restrict__ flags) {
    __shared__ int sm[256];
    __shared__ int runD[256], runS[256];
    int b = blockIdx.x, t = threadIdx.x;
    int v = btotD[t];
    sm[t] = v;
    __syncthreads();
    for (int off = 1; off < 256; off <<= 1) {
        int u = (t >= off) ? sm[t - off] : 0;
        __syncthreads();
        sm[t] += u;
        __syncthreads();
    }
    int baseD = sm[t] - v;
    __syncthreads();
    v = btotS[t];
    sm[t] = v;
    __syncthreads();
    for (int off = 1; off < 256; off <<= 1) {
        int u = (t >= off) ? sm[t - off] : 0;
        __syncthreads();
        sm[t] += u;
        __syncthreads();
    }
    int baseS = sm[t] - v;
    runD[t] = baseD + offD[b * 256 + t];
    runS[t] = baseS + offS[b * 256 + t];
    __syncthreads();
    int is64 = flags[2];
    int base = b * EPB;
#pragma unroll
    for (int i = 0; i < EPB / 256; ++i) {
        int e = base + i * 256 + t;
        if (e < N_EDGES) {
            int d = load_idx(dst, e, is64);
            int s = load_idx(src, e, is64);
            int pd = atomicAdd(&runD[d >> 8], 1);
            epack[pd] = ((unsigned)(d & 255) << 16) | (unsigned)s;
            int ps = atomicAdd(&runS[s >> 8], 1);
            sloc[ps] = (unsigned char)(s & 255);
        }
    }
}

// ---------------- pass 4: CSR build + norms + esrc + folded h->A0 cvt ----------------

__global__ __launch_bounds__(256) void bucket_build(const unsigned* __restrict__ epack,
                                                    const int* __restrict__ btotD,
                                                    const unsigned char* __restrict__ sloc,
                                                    const int* __restrict__ btotS,
                                                    int* __restrict__ rowptr,
                                                    float* __restrict__ normD,
                                                    float* __restrict__ normS,
                                                    unsigned short* __restrict__ esrc,
                                                    const void* __restrict__ h,
                                                    unsigned short* __restrict__ A0,
                                                    const int* __restrict__ flags) {
    __shared__ int bD[256], bS[256], cnt[256], run[256];
    __shared__ float nsf[256];
    int k = blockIdx.x, t = threadIdx.x;
    int vD = btotD[t], vS = btotS[t];
    bD[t] = vD; bS[t] = vS;
    __syncthreads();
    for (int off = 1; off < 256; off <<= 1) {
        int uD = (t >= off) ? bD[t - off] : 0;
        int uS = (t >= off) ? bS[t - off] : 0;
        __syncthreads();
        bD[t] += uD; bS[t] += uS;
        __syncthreads();
    }
    int ebeg = (k == 0) ? 0 : bD[k - 1];
    int eend = bD[k];
    int sbeg = (k == 0) ? 0 : bS[k - 1];
    int send = bS[k];

    cnt[t] = 0;
    __syncthreads();
    for (int e = ebeg + t; e < eend; e += 256)
        atomicAdd(&cnt[epack[e] >> 16], 1);
    __syncthreads();
    int v = cnt[t];
    bD[t] = v;  // reuse as scan buffer
    __syncthreads();
    for (int off = 1; off < 256; off <<= 1) {
        int u = (t >= off) ? bD[t - off] : 0;
        __syncthreads();
        bD[t] += u;
        __syncthreads();
    }
    int excl = bD[t] - v;
    int n = k * 256 + t;
    if (n < N_NODES) {
        rowptr[n] = ebeg + excl;
        normD[n] = rsqrtf((float)max(v, 1));
    }
    run[t] = excl;
    __syncthreads();
    for (int e = ebeg + t; e < eend; e += 256) {
        unsigned p = epack[e];
        int dl = p >> 16;
        int slot = atomicAdd(&run[dl], 1);
        esrc[ebeg + slot] = (unsigned short)(p & 0xFFFFu);
    }
    if (k == NBKT - 1 && t == 0) rowptr[N_NODES] = N_EDGES;
    // src histogram -> normS (kept in LDS for the cvt fold)
    __syncthreads();
    cnt[t] = 0;
    __syncthreads();
    for (int e = sbeg + t; e < send; e += 256)
        atomicAdd(&cnt[sloc[e]], 1);
    __syncthreads();
    float ns = rsqrtf((float)max(cnt[t], 1));
    nsf[t] = ns;
    if (n < N_NODES) normS[n] = ns;
    __syncthreads();
    // folded cvt: A0[n] = bf16(h[n] * normS[n]) for this block's 256 nodes
    int hbf = flags[0];
    for (int i = t; i < 256 * (DIM / 4); i += 256) {
        int ln_ = i / (DIM / 4);
        int c4 = i - ln_ * (DIM / 4);
        int nn = k * 256 + ln_;
        if (nn >= N_NODES) continue;
        float s = nsf[ln_];
        float v0, v1, v2, v3;
        if (hbf) {
            const __hip_bfloat16* hp = (const __hip_bfloat16*)h + (size_t)nn * DIM + c4 * 4;
            v0 = __bfloat162float(hp[0]); v1 = __bfloat162float(hp[1]);
            v2 = __bfloat162float(hp[2]); v3 = __bfloat162float(hp[3]);
        } else {
            float4 vv = ((const float4*)h)[nn * (DIM / 4) + c4];
            v0 = vv.x; v1 = vv.y; v2 = vv.z; v3 = vv.w;
        }
        ushort4 o;
        o.x = f2bf(v0 * s); o.y = f2bf(v1 * s);
        o.z = f2bf(v2 * s); o.w = f2bf(v3 * s);
        ((ushort4*)A0)[nn * (DIM / 4) + c4] = o;
    }
}

// ---------------- fused layer: gather (-> LDS) + MFMA GEMM + epilogue ----------------
// Per block: 64 dst rows. Gather phase: 768 (row,chunk) items, 3/thread, fp32 acc,
// bf16-pack into 14.3KB LDS tile (row stride 112 bf16 -> 16B-aligned ds_read_b128).
// One __syncthreads. MFMA phase: A-frags from LDS, B-frags from W^T in L2.
// Small LDS + no W staging keeps occupancy gather-grade (R6 fix).

template <bool LAST>
__global__ __launch_bounds__(256) void fused_layer(const unsigned* __restrict__ Abf,
                                                   const float* __restrict__ normS,
                                                   const float* __restrict__ normD,
                                                   const int* __restrict__ rowptr,
                                                   const unsigned short* __restrict__ esrc,
                                                   const unsigned short* __restrict__ WTl,
                                                   const float* __restrict__ bl,
                                                   unsigned short* __restrict__ outA,
                                                   void* __restrict__ outLast,
                                                   const int* __restrict__ flags) {
    __shared__ unsigned short Bs[64 * LROW];  // 14336 B

    const uint4* Ap = (const uint4*)Abf;
    int row0 = blockIdx.x * 64;

#pragma unroll
    for (int it = 0; it < 3; ++it) {
        int g = threadIdx.x + 256 * it;       // 0..767
        int r = g / CHB;
        int c = g - r * CHB;
        int n = row0 + r;
        float a[8] = {0.f, 0.f, 0.f, 0.f, 0.f, 0.f, 0.f, 0.f};
        float nd = 0.f;
        if (n < N_NODES) {
            int beg = rowptr[n], end = rowptr[n + 1];
            int k = beg;
            for (; k + 4 <= end; k += 4) {
                int s0 = esrc[k], s1 = esrc[k + 1], s2 = esrc[k + 2], s3 = esrc[k + 3];
                uint4 q0 = Ap[s0 * CHB + c];
                uint4 q1 = Ap[s1 * CHB + c];
                uint4 q2 = Ap[s2 * CHB + c];
                uint4 q3 = Ap[s3 * CHB + c];
                acc8(a, q0); acc8(a, q1); acc8(a, q2); acc8(a, q3);
            }
            for (; k < end; ++k) acc8(a, Ap[esrc[k] * CHB + c]);
            nd = normD[n];
        }
        uint4 o;
        o.x = (unsigned)f2bf(a[0] * nd) | ((unsigned)f2bf(a[1] * nd) << 16);
        o.y = (unsigned)f2bf(a[2] * nd) | ((unsigned)f2bf(a[3] * nd) << 16);
        o.z = (unsigned)f2bf(a[4] * nd) | ((unsigned)f2bf(a[5] * nd) << 16);
        o.w = (unsigned)f2bf(a[6] * nd) | ((unsigned)f2bf(a[7] * nd) << 16);
        *(uint4*)&Bs[r * LROW + c * 8] = o;
    }
    __syncthreads();

    int wv = threadIdx.x >> 6;
    int lane = threadIdx.x & 63;
    int quad = lane >> 4;
    int ln = lane & 15;
    int rl = wv * 16 + ln;
    int rowbase = row0 + wv * 16;

    short8 a0 = *(const short8*)&Bs[rl * LROW + quad * 8];
    short8 a1 = *(const short8*)&Bs[rl * LROW + 32 + quad * 8];
    short8 a2 = *(const short8*)&Bs[rl * LROW + 64 + quad * 8];

    float ns[4];
    if (!LAST) {
#pragma unroll
        for (int r = 0; r < 4; ++r)
            ns[r] = normS[min(rowbase + quad * 4 + r, N_NODES - 1)];
    }
    int obf = flags[0];

#pragma unroll
    for (int ct = 0; ct < 6; ++ct) {
        const short8* Wp = (const short8*)(WTl + (size_t)(ct * 16 + ln) * DIM + quad * 8);
        short8 b0 = Wp[0], b1 = Wp[4], b2 = Wp[8];
        f32x4 acc = {0.f, 0.f, 0.f, 0.f};
        acc = __builtin_amdgcn_mfma_f32_16x16x32_bf16(a0, b0, acc, 0, 0, 0);
        acc = __builtin_amdgcn_mfma_f32_16x16x32_bf16(a1, b1, acc, 0, 0, 0);
        acc = __builtin_amdgcn_mfma_f32_16x16x32_bf16(a2, b2, acc, 0, 0, 0);
        int col = ct * 16 + ln;
        float bv = bl[col];
#pragma unroll
        for (int r = 0; r < 4; ++r) {
            int row = rowbase + quad * 4 + r;
            if (row < N_NODES) {
                float v = fmaxf(acc[r] + bv, 0.f);
                size_t idx = (size_t)row * DIM + col;
                if (LAST) {
                    if (obf)
                        ((__hip_bfloat16*)outLast)[idx] = __float2bfloat16(v);
                    else
                        ((float*)outLast)[idx] = v;
                } else {
                    outA[idx] = f2bf(v * ns[r]);
                }
            }
        }
    }
}

// ---------------- host launch ----------------

extern "C" void kernel_launch(void* const* d_in, const int* in_sizes, int n_in,
                              void* d_out, int out_size, void* d_ws, size_t ws_size,
                              hipStream_t stream) {
    const void* h = d_in[0];
    const int* src = (const int*)d_in[1];
    const int* dst = (const int*)d_in[2];

    // workspace layout (4B units; all sections 16B-aligned)
    int* flags = (int*)d_ws;                            // 4
    int* cntD = flags + 4;                              // 100096
    int* cntS = cntD + NB_E * 256;                      // 100096
    int* btotD = cntS + NB_E * 256;                     // 256
    int* btotS = btotD + 256;                           // 256
    int* rowptr = btotS + 256;                          // 50004
    float* normS = (float*)(rowptr + 50004);            // 50000
    float* normD = normS + N_NODES;                     // 50000
    unsigned short* WT = (unsigned short*)(normD + N_NODES);  // 3*9216 us
    float* biasc = (float*)(WT + 3 * DIM * DIM);        // 288
    unsigned* epack = (unsigned*)(biasc + 3 * DIM);     // 800000
    unsigned char* sloc = (unsigned char*)(epack + N_EDGES);   // 800000 B
    unsigned short* esrc = (unsigned short*)(sloc + N_EDGES);  // 800000 us
    unsigned short* A0 = esrc + N_EDGES;                // 4.8M us
    unsigned short* A1 = A0 + (size_t)N_NODES * DIM;    // 4.8M us

    part_count<<<NB_E, 256, 0, stream>>>(src, dst, (const unsigned*)h,
                                         (const unsigned*)d_in[3], cntD, cntS, flags);
    scan_buckets<<<256, 256, 0, stream>>>(cntD, cntS, btotD, btotS,
                                          d_in[3], d_in[5], d_in[7],
                                          d_in[4], d_in[6], d_in[8],
                                          WT, biasc, flags);
    part_scatter<<<NB_E, 256, 0, stream>>>(src, dst, cntD, cntS, btotD, btotS,
                                           epack, sloc, flags);
    bucket_build<<<NBKT, 256, 0, stream>>>(epack, btotD, sloc, btotS,
                                           rowptr, normD, normS, esrc,
                                           h, A0, flags);

    fused_layer<false><<<NTILES, 256, 0, stream>>>((const unsigned*)A0, normS, normD,
                                                   rowptr, esrc, WT, biasc,
                                                   A1, nullptr, flags);
    fused_layer<false><<<NTILES, 256, 0, stream>>>((const unsigned*)A1, normS, normD,
                                                   rowptr, esrc, WT + DIM * DIM, biasc + DIM,
                                                   A0, nullptr, flags);
    fused_layer<true><<<NTILES, 256, 0, stream>>>((const unsigned*)A0, normS, normD,
                                                  rowptr, esrc, WT + 2 * DIM * DIM,
                                                  biasc + 2 * DIM, nullptr, d_out, flags);
}

// Round 16
// 248.686 us; speedup vs baseline: 1.0668x; 1.0668x over previous
//
#include <hip/hip_runtime.h>
#include <hip/hip_bf16.h>

#define N_NODES 50000
#define N_PAD 50048  // Bm rows padded so MFMA frag loads stay in-bounds
#define N_EDGES 800000
#define DIM 96
#define CHB 12  // bf16 row = 96*2B = 12 x 16B chunks (8 features/thread)

#define EPB 2048                                   // edges per partition block
#define NB_E ((N_EDGES + EPB - 1) / EPB)           // 391
#define NBKT ((N_NODES + 255) / 256)               // 196 buckets of 256 nodes

typedef __attribute__((ext_vector_type(8))) short short8;  // 8 bf16 = 4 VGPRs
typedef __attribute__((ext_vector_type(4))) float f32x4;

// Lessons locked in (R12-R14): launch boundaries cost ~2-3us here — folding
// kernels to save launches loses more in parallelism than it saves (fused_layer
// at 782 blocks = 12 waves/CU starved the latency-bound gather; cooperative
// grid.sync() costs ~250us/sync across 8 non-coherent XCD L2s). This is the
// best-measured R11 configuration: standalone max-TLP gather + no-LDS MFMA GEMM.
// R15 note: identical source core-dumped once — treated as infra flake (no diff
// vs R11 which passed); this is the controlled retry.

// ---------------- dtype detection (wave-parallel, graph-capture safe) ----------------
// flags[0] = h is bf16, flags[1] = W/b are bf16, flags[2] = indices are int64

__device__ __forceinline__ int good_halves(unsigned w) {
    unsigned lo = w & 0xFFFFu, hi = w >> 16;
    unsigned e0 = (lo >> 7) & 0xFF, e1 = (hi >> 7) & 0xFF;
    int g = 0;
    if (lo == 0 || (e0 >= 100 && e0 <= 140)) ++g;
    if (hi == 0 || (e1 >= 100 && e1 <= 140)) ++g;
    return g;
}

__global__ void detect_kernel(const unsigned* __restrict__ hw,
                              const unsigned* __restrict__ ww,
                              const unsigned* __restrict__ sw,
                              int* __restrict__ flags) {
    int t = threadIdx.x;  // 64 threads = 1 wave
    int gh = good_halves(hw[t]) + good_halves(hw[64 + t]);
    int gw = good_halves(ww[t]) + good_halves(ww[64 + t]);
    int gz = (sw[2 * t + 1] == 0u) ? 1 : 0;
#pragma unroll
    for (int off = 32; off > 0; off >>= 1) {
        gh += __shfl_down(gh, off);
        gw += __shfl_down(gw, off);
        gz += __shfl_down(gz, off);
    }
    if (t == 0) {
        flags[0] = (gh >= 226) ? 1 : 0;
        flags[1] = (gw >= 226) ? 1 : 0;
        flags[2] = (gz >= 60) ? 1 : 0;
    }
}

__device__ __forceinline__ int load_idx(const int* __restrict__ p, int e, int is64) {
    return p[is64 ? (e << 1) : e];
}

// round-to-nearest-even fp32 -> bf16 bits (finite inputs only)
__device__ __forceinline__ unsigned short f2bf(float f) {
    unsigned u = __float_as_uint(f);
    u += 0x7FFFu + ((u >> 16) & 1u);
    return (unsigned short)(u >> 16);
}

// ---------------- pass 1: per-block bucket counts (LDS histograms) ----------------

__global__ __launch_bounds__(256) void part_count(const int* __restrict__ src,
                                                  const int* __restrict__ dst,
                                                  int* __restrict__ cntD,
                                                  int* __restrict__ cntS,
                                                  const int* __restrict__ flags) {
    __shared__ int lcD[256], lcS[256];
    int b = blockIdx.x, t = threadIdx.x;
    lcD[t] = 0; lcS[t] = 0;
    __syncthreads();
    int is64 = flags[2];
    int base = b * EPB;
#pragma unroll
    for (int i = 0; i < EPB / 256; ++i) {
        int e = base + i * 256 + t;
        if (e < N_EDGES) {
            int d = load_idx(dst, e, is64);
            int s = load_idx(src, e, is64);
            atomicAdd(&lcD[d >> 8], 1);
            atomicAdd(&lcS[s >> 8], 1);
        }
    }
    __syncthreads();
    cntD[b * 256 + t] = lcD[t];
    cntS[b * 256 + t] = lcS[t];
}

// ---------------- pass 2a: per-bucket exclusive scan over blocks (in-place) --------

__global__ __launch_bounds__(256) void scan_buckets(int* __restrict__ cntD,
                                                    int* __restrict__ cntS,
                                                    int* __restrict__ btotD,
                                                    int* __restrict__ btotS) {
    __shared__ int sm[256];
    int k = blockIdx.x, t = threadIdx.x;
    int b0 = 2 * t, b1 = 2 * t + 1;
    int v0 = (b0 < NB_E) ? cntD[b0 * 256 + k] : 0;
    int v1 = (b1 < NB_E) ? cntD[b1 * 256 + k] : 0;
    int pair = v0 + v1;
    sm[t] = pair;
    __syncthreads();
    for (int off = 1; off < 256; off <<= 1) {
        int u = (t >= off) ? sm[t - off] : 0;
        __syncthreads();
        sm[t] += u;
        __syncthreads();
    }
    int excl = sm[t] - pair;
    if (b0 < NB_E) cntD[b0 * 256 + k] = excl;
    if (b1 < NB_E) cntD[b1 * 256 + k] = excl + v0;
    if (t == 255) btotD[k] = sm[255];
    __syncthreads();
    v0 = (b0 < NB_E) ? cntS[b0 * 256 + k] : 0;
    v1 = (b1 < NB_E) ? cntS[b1 * 256 + k] : 0;
    pair = v0 + v1;
    sm[t] = pair;
    __syncthreads();
    for (int off = 1; off < 256; off <<= 1) {
        int u = (t >= off) ? sm[t - off] : 0;
        __syncthreads();
        sm[t] += u;
        __syncthreads();
    }
    excl = sm[t] - pair;
    if (b0 < NB_E) cntS[b0 * 256 + k] = excl;
    if (b1 < NB_E) cntS[b1 * 256 + k] = excl + v0;
    if (t == 255) btotS[k] = sm[255];
}

// ---------------- pass 2b: bucket bases ----------------

__global__ __launch_bounds__(256) void scan_bases(const int* __restrict__ btotD,
                                                  const int* __restrict__ btotS,
                                                  int* __restrict__ bbaseD,
                                                  int* __restrict__ bbaseS) {
    __shared__ int sm[256];
    int t = threadIdx.x;
    int v = btotD[t];
    sm[t] = v;
    __syncthreads();
    for (int off = 1; off < 256; off <<= 1) {
        int u = (t >= off) ? sm[t - off] : 0;
        __syncthreads();
        sm[t] += u;
        __syncthreads();
    }
    bbaseD[t] = sm[t] - v;
    if (t == 255) bbaseD[256] = sm[255];
    __syncthreads();
    v = btotS[t];
    sm[t] = v;
    __syncthreads();
    for (int off = 1; off < 256; off <<= 1) {
        int u = (t >= off) ? sm[t - off] : 0;
        __syncthreads();
        sm[t] += u;
        __syncthreads();
    }
    bbaseS[t] = sm[t] - v;
    if (t == 255) bbaseS[256] = sm[255];
}

// ---------------- pass 3: scatter into buckets (LDS running counters) ----------------

__global__ __launch_bounds__(256) void part_scatter(const int* __restrict__ src,
                                                    const int* __restrict__ dst,
                                                    const int* __restrict__ offD,
                                                    const int* __restrict__ offS,
                                                    const int* __restrict__ bbaseD,
                                                    const int* __restrict__ bbaseS,
                                                    unsigned* __restrict__ epack,
                                                    unsigned char* __restrict__ sloc,
                                                    const int* __restrict__ flags) {
    __shared__ int runD[256], runS[256];
    int b = blockIdx.x, t = threadIdx.x;
    runD[t] = bbaseD[t] + offD[b * 256 + t];
    runS[t] = bbaseS[t] + offS[b * 256 + t];
    __syncthreads();
    int is64 = flags[2];
    int base = b * EPB;
#pragma unroll
    for (int i = 0; i < EPB / 256; ++i) {
        int e = base + i * 256 + t;
        if (e < N_EDGES) {
            int d = load_idx(dst, e, is64);
            int s = load_idx(src, e, is64);
            int pd = atomicAdd(&runD[d >> 8], 1);
            epack[pd] = ((unsigned)(d & 255) << 16) | (unsigned)s;
            int ps = atomicAdd(&runS[s >> 8], 1);
            sloc[ps] = (unsigned char)(s & 255);
        }
    }
}

// ---------------- pass 4: per-bucket CSR build + normD + esrc + src-hist -> normS ----

__global__ __launch_bounds__(256) void bucket_build(const unsigned* __restrict__ epack,
                                                    const int* __restrict__ bbaseD,
                                                    const unsigned char* __restrict__ sloc,
                                                    const int* __restrict__ bbaseS,
                                                    int* __restrict__ rowptr,
                                                    float* __restrict__ normD,
                                                    float* __restrict__ normS,
                                                    unsigned short* __restrict__ esrc) {
    __shared__ int cnt[256];
    __shared__ int scan[256];
    __shared__ int run[256];
    int k = blockIdx.x, t = threadIdx.x;
    int ebeg = bbaseD[k], eend = bbaseD[k + 1];
    cnt[t] = 0;
    __syncthreads();
    for (int e = ebeg + t; e < eend; e += 256)
        atomicAdd(&cnt[epack[e] >> 16], 1);
    __syncthreads();
    int v = cnt[t];
    scan[t] = v;
    __syncthreads();
    for (int off = 1; off < 256; off <<= 1) {
        int u = (t >= off) ? scan[t - off] : 0;
        __syncthreads();
        scan[t] += u;
        __syncthreads();
    }
    int excl = scan[t] - v;
    int n = k * 256 + t;
    if (n < N_NODES) {
        rowptr[n] = ebeg + excl;
        normD[n] = rsqrtf((float)max(v, 1));
    }
    run[t] = excl;
    __syncthreads();
    for (int e = ebeg + t; e < eend; e += 256) {
        unsigned p = epack[e];
        int dl = p >> 16;
        int slot = atomicAdd(&run[dl], 1);
        esrc[ebeg + slot] = (unsigned short)(p & 0xFFFFu);
    }
    if (k == NBKT - 1 && t == 0) rowptr[N_NODES] = N_EDGES;
    // ---- src histogram phase -> normS ----
    __syncthreads();
    cnt[t] = 0;
    __syncthreads();
    int sbeg = bbaseS[k], send = bbaseS[k + 1];
    for (int e = sbeg + t; e < send; e += 256)
        atomicAdd(&cnt[sloc[e]], 1);
    __syncthreads();
    if (n < N_NODES) normS[n] = rsqrtf((float)max(cnt[t], 1));
}

// ---------------- prep: W^T bf16 + bias fp32, fully parallel ----------------

__global__ __launch_bounds__(256) void prep_w(const void* __restrict__ W0,
                                              const void* __restrict__ W1,
                                              const void* __restrict__ W2,
                                              const void* __restrict__ b0,
                                              const void* __restrict__ b1,
                                              const void* __restrict__ b2,
                                              unsigned short* __restrict__ WT,
                                              float* __restrict__ biasc,
                                              const int* __restrict__ flags) {
    int idx = blockIdx.x * 256 + threadIdx.x;
    int wbf = flags[1];
    if (idx < 3 * DIM * DIM) {
        int l = idx / (DIM * DIM);
        int i = idx - l * DIM * DIM;
        int k = i / DIM, n = i - k * DIM;
        const void* Wp = (l == 0) ? W0 : (l == 1) ? W1 : W2;
        float v = wbf ? __bfloat162float(((const __hip_bfloat16*)Wp)[i])
                      : ((const float*)Wp)[i];
        WT[l * DIM * DIM + n * DIM + k] = f2bf(v);
    } else if (idx < 3 * DIM * DIM + 3 * DIM) {
        int j = idx - 3 * DIM * DIM;
        int l = j / DIM;
        int c = j - l * DIM;
        const void* bp = (l == 0) ? b0 : (l == 1) ? b1 : b2;
        float v = wbf ? __bfloat162float(((const __hip_bfloat16*)bp)[c])
                      : ((const float*)bp)[c];
        biasc[j] = v;
    }
}

// ---------------- cvt: A0 = bf16(h * normS) ----------------

__global__ __launch_bounds__(256) void cvt_kernel(const void* __restrict__ h,
                                                  const float* __restrict__ normS,
                                                  unsigned short* __restrict__ out,
                                                  const int* __restrict__ flags) {
    int i4 = blockIdx.x * 256 + threadIdx.x;  // 4 elems per thread
    if (i4 >= N_NODES * DIM / 4) return;
    int i = i4 * 4;
    float ns = normS[i / DIM];
    float v0, v1, v2, v3;
    if (flags[0]) {
        const __hip_bfloat16* hp = (const __hip_bfloat16*)h + i;
        v0 = __bfloat162float(hp[0]); v1 = __bfloat162float(hp[1]);
        v2 = __bfloat162float(hp[2]); v3 = __bfloat162float(hp[3]);
    } else {
        float4 v = ((const float4*)h)[i4];
        v0 = v.x; v1 = v.y; v2 = v.z; v3 = v.w;
    }
    ushort4 o;
    o.x = f2bf(v0 * ns); o.y = f2bf(v1 * ns);
    o.z = f2bf(v2 * ns); o.w = f2bf(v3 * ns);
    ((ushort4*)out)[i4] = o;
}

// ---------------- gather: Bm[n] = bf16(normD[n] * sum Abf[esrc[e]]) ----------------
// 12 threads/row, 8 bf16 features (16B uint4) each; fp32 accumulation; unroll x2.
// Standalone (no LDS, 2344 blocks -> 32 waves/CU) keeps the dependent-load chain
// latency-hidden by TLP (R6/R14 lesson: any fusion that cuts this TLP loses).

__global__ __launch_bounds__(256) void gather_kernel(const unsigned* __restrict__ Abf,
                                                     const float* __restrict__ normD,
                                                     const int* __restrict__ rowptr,
                                                     const unsigned short* __restrict__ esrc,
                                                     unsigned short* __restrict__ Bm) {
    int g = blockIdx.x * 256 + threadIdx.x;
    if (g >= N_NODES * CHB) return;
    int n = g / CHB;
    int c = g - n * CHB;
    int beg = rowptr[n], end = rowptr[n + 1];
    float a0 = 0.f, a1 = 0.f, a2 = 0.f, a3 = 0.f;
    float a4 = 0.f, a5 = 0.f, a6 = 0.f, a7 = 0.f;
    const uint4* Ap = (const uint4*)Abf;
    int k = beg;
    for (; k + 2 <= end; k += 2) {
        int s0 = esrc[k], s1 = esrc[k + 1];
        uint4 q = Ap[s0 * CHB + c];
        uint4 r = Ap[s1 * CHB + c];
        a0 += __uint_as_float(q.x << 16);
        a1 += __uint_as_float(q.x & 0xFFFF0000u);
        a2 += __uint_as_float(q.y << 16);
        a3 += __uint_as_float(q.y & 0xFFFF0000u);
        a4 += __uint_as_float(q.z << 16);
        a5 += __uint_as_float(q.z & 0xFFFF0000u);
        a6 += __uint_as_float(q.w << 16);
        a7 += __uint_as_float(q.w & 0xFFFF0000u);
        a0 += __uint_as_float(r.x << 16);
        a1 += __uint_as_float(r.x & 0xFFFF0000u);
        a2 += __uint_as_float(r.y << 16);
        a3 += __uint_as_float(r.y & 0xFFFF0000u);
        a4 += __uint_as_float(r.z << 16);
        a5 += __uint_as_float(r.z & 0xFFFF0000u);
        a6 += __uint_as_float(r.w << 16);
        a7 += __uint_as_float(r.w & 0xFFFF0000u);
    }
    if (k < end) {
        int s0 = esrc[k];
        uint4 q = Ap[s0 * CHB + c];
        a0 += __uint_as_float(q.x << 16);
        a1 += __uint_as_float(q.x & 0xFFFF0000u);
        a2 += __uint_as_float(q.y << 16);
        a3 += __uint_as_float(q.y & 0xFFFF0000u);
        a4 += __uint_as_float(q.z << 16);
        a5 += __uint_as_float(q.z & 0xFFFF0000u);
        a6 += __uint_as_float(q.w << 16);
        a7 += __uint_as_float(q.w & 0xFFFF0000u);
    }
    float nd = normD[n];
    uint4 o;
    o.x = (unsigned)f2bf(a0 * nd) | ((unsigned)f2bf(a1 * nd) << 16);
    o.y = (unsigned)f2bf(a2 * nd) | ((unsigned)f2bf(a3 * nd) << 16);
    o.z = (unsigned)f2bf(a4 * nd) | ((unsigned)f2bf(a5 * nd) << 16);
    o.w = (unsigned)f2bf(a6 * nd) | ((unsigned)f2bf(a7 * nd) << 16);
    ((uint4*)Bm)[g] = o;
}

// ---------------- MFMA GEMM: t = relu(Bm @ W + b) ----------------
// No LDS, no barriers. 4 waves/block, 16 output rows each. A-frags direct from
// global Bm (A[m=lane&15][k=quad*8+j]); B-frags from precomputed W^T bf16
// (B[n=lane&15][k=quad*8+j]); C/D: col=lane&15, row=quad*4+reg (m89/m91).

template <bool LAST>
__global__ __launch_bounds__(256) void mfma_gemm(const unsigned short* __restrict__ Bm,
                                                 const float* __restrict__ normS,
                                                 const unsigned short* __restrict__ WT,
                                                 const float* __restrict__ biasc,
                                                 unsigned short* __restrict__ outA,
                                                 void* __restrict__ outLast,
                                                 const int* __restrict__ flags) {
    int wv = threadIdx.x >> 6;
    int lane = threadIdx.x & 63;
    int quad = lane >> 4;
    int ln = lane & 15;
    int rowbase = blockIdx.x * 64 + wv * 16;

    const short8* Ap = (const short8*)(Bm + (size_t)(rowbase + ln) * DIM + quad * 8);
    short8 a0 = Ap[0];   // k: quad*8 + [0,8)
    short8 a1 = Ap[4];   // +32
    short8 a2 = Ap[8];   // +64

    float ns[4];
    if (!LAST) {
#pragma unroll
        for (int r = 0; r < 4; ++r)
            ns[r] = normS[min(rowbase + quad * 4 + r, N_NODES - 1)];
    }
    int obf = flags[0];

#pragma unroll
    for (int ct = 0; ct < 6; ++ct) {
        const short8* Wp = (const short8*)(WT + (size_t)(ct * 16 + ln) * DIM + quad * 8);
        short8 b0 = Wp[0], b1 = Wp[4], b2 = Wp[8];
        f32x4 acc = {0.f, 0.f, 0.f, 0.f};
        acc = __builtin_amdgcn_mfma_f32_16x16x32_bf16(a0, b0, acc, 0, 0, 0);
        acc = __builtin_amdgcn_mfma_f32_16x16x32_bf16(a1, b1, acc, 0, 0, 0);
        acc = __builtin_amdgcn_mfma_f32_16x16x32_bf16(a2, b2, acc, 0, 0, 0);
        int col = ct * 16 + ln;
        float bv = biasc[col];
#pragma unroll
        for (int r = 0; r < 4; ++r) {
            int row = rowbase + quad * 4 + r;
            if (row < N_NODES) {
                float v = fmaxf(acc[r] + bv, 0.f);
                size_t idx = (size_t)row * DIM + col;
                if (LAST) {
                    if (obf)
                        ((__hip_bfloat16*)outLast)[idx] = __float2bfloat16(v);
                    else
                        ((float*)outLast)[idx] = v;
                } else {
                    outA[idx] = f2bf(v * ns[r]);
                }
            }
        }
    }
}

// ---------------- host launch ----------------

extern "C" void kernel_launch(void* const* d_in, const int* in_sizes, int n_in,
                              void* d_out, int out_size, void* d_ws, size_t ws_size,
                              hipStream_t stream) {
    const void* h = d_in[0];
    const int* src = (const int*)d_in[1];
    const int* dst = (const int*)d_in[2];

    // workspace layout (4B units; every offset stays 16B-aligned)
    int* flags = (int*)d_ws;                            // 4
    int* cntD = flags + 4;                              // 100096
    int* cntS = cntD + NB_E * 256;                      // 100096
    int* btotD = cntS + NB_E * 256;                     // 256
    int* btotS = btotD + 256;                           // 256
    int* bbaseD = btotS + 256;                          // 260
    int* bbaseS = bbaseD + 260;                         // 260
    int* rowptr = bbaseS + 260;                         // 50004
    float* normS = (float*)(rowptr + 50004);            // 50000
    float* normD = normS + N_NODES;                     // 50000
    unsigned short* WT = (unsigned short*)(normD + N_NODES);  // 3*9216 us
    float* biasc = (float*)(WT + 3 * DIM * DIM);        // 288
    unsigned* epack = (unsigned*)(biasc + 3 * DIM);     // 800000
    unsigned char* sloc = (unsigned char*)(epack + N_EDGES);   // 800000 B
    unsigned short* esrc = (unsigned short*)(sloc + N_EDGES);  // 800000 us
    unsigned short* Bm = esrc + N_EDGES;                // N_PAD*96 us
    unsigned short* A0 = Bm + (size_t)N_PAD * DIM;      // 4.8M us
    unsigned short* A1 = A0 + (size_t)N_NODES * DIM;    // 4.8M us

    detect_kernel<<<1, 64, 0, stream>>>((const unsigned*)h, (const unsigned*)d_in[3],
                                        (const unsigned*)src, flags);

    part_count<<<NB_E, 256, 0, stream>>>(src, dst, cntD, cntS, flags);
    scan_buckets<<<256, 256, 0, stream>>>(cntD, cntS, btotD, btotS);
    scan_bases<<<1, 256, 0, stream>>>(btotD, btotS, bbaseD, bbaseS);
    part_scatter<<<NB_E, 256, 0, stream>>>(src, dst, cntD, cntS, bbaseD, bbaseS,
                                           epack, sloc, flags);
    bucket_build<<<NBKT, 256, 0, stream>>>(epack, bbaseD, sloc, bbaseS,
                                           rowptr, normD, normS, esrc);
    prep_w<<<(3 * DIM * DIM + 3 * DIM + 255) / 256, 256, 0, stream>>>(
        d_in[3], d_in[5], d_in[7], d_in[4], d_in[6], d_in[8], WT, biasc, flags);
    cvt_kernel<<<(N_NODES * DIM / 4 + 255) / 256, 256, 0, stream>>>(h, normS, A0, flags);

    const int gather_grid = (N_NODES * CHB + 255) / 256;
    const int gemm_grid = (N_NODES + 63) / 64;

    // layer 0
    gather_kernel<<<gather_grid, 256, 0, stream>>>((const unsigned*)A0, normD, rowptr, esrc, Bm);
    mfma_gemm<false><<<gemm_grid, 256, 0, stream>>>(Bm, normS, WT, biasc, A1, nullptr, flags);
    // layer 1
    gather_kernel<<<gather_grid, 256, 0, stream>>>((const unsigned*)A1, normD, rowptr, esrc, Bm);
    mfma_gemm<false><<<gemm_grid, 256, 0, stream>>>(Bm, normS, WT + DIM * DIM, biasc + DIM,
                                                    A0, nullptr, flags);
    // layer 2
    gather_kernel<<<gather_grid, 256, 0, stream>>>((const unsigned*)A0, normD, rowptr, esrc, Bm);
    mfma_gemm<true><<<gemm_grid, 256, 0, stream>>>(Bm, normS, WT + 2 * DIM * DIM, biasc + 2 * DIM,
                                                   nullptr, d_out, flags);
}